// Round 1
// 405.394 us; speedup vs baseline: 1.2122x; 1.2122x over previous
//
#include <hip/hip_runtime.h>
#include <cstdint>
#include <cstddef>

typedef short bf16x8 __attribute__((ext_vector_type(8)));
typedef float f32x4 __attribute__((ext_vector_type(4)));

// ---- problem constants ----
// B=8, H=W=128, C=256, heads=8, hd=32, ws=8, shift=4, N=64 tokens/window,
// 16x16 windows/image, 2048 windows total.

// ---- workspace layout (byte offsets) ----
#define WS_QKVW   0u          // bf16 [768][256]
#define WS_PROJW  393216u     // bf16 [256][256]
#define WS_QKVB   524288u     // f32  [768]  (q_bias, 0, v_bias)
#define WS_SCALE  527360u     // f32  [8]    exp(min(logit_scale, ln 100))
#define WS_BT     527392u     // f32  [225][8] cpb table
#define WS_BIAS   534592u     // f32  [8][4(jt)][4(it)][64][4]  (S^T-layout swizzled)
// total needed: 665664 bytes

// ---- LDS layout (ushort units) ----
// X window [64][264] (reused as attn_out), then 8 per-wave scratch bufs of
// 2560 us each (q-T -> k-T -> V^T[32][72] -> P half [64][40], timeshared).
#define XS_US   0
#define SCR_US  16896
#define SMEM_US (16896 + 8 * 2560)   // 37376 us
#define SMEM_BYTES (SMEM_US * 2)     // 74752 B -> 2 blocks/CU (<= 81920)

__device__ __forceinline__ unsigned short f2b(float f) {
  union { float f; unsigned int u; } v; v.f = f;
  return (unsigned short)((v.u + 0x7FFFu + ((v.u >> 16) & 1u)) >> 16);
}
__device__ __forceinline__ float b2f(unsigned short h) {
  union { unsigned int u; float f; } v; v.u = ((unsigned int)h) << 16;
  return v.f;
}

// ---------------- prep kernels ----------------

__global__ void prep_weights(const float* __restrict__ qkv_w,
                             const float* __restrict__ q_bias,
                             const float* __restrict__ v_bias,
                             const float* __restrict__ logit_scale,
                             const float* __restrict__ proj_w,
                             unsigned char* __restrict__ ws) {
  int gid = blockIdx.x * 256 + threadIdx.x;            // 0 .. 196607
  unsigned short* qw = (unsigned short*)(ws + WS_QKVW);
  unsigned short* pw = (unsigned short*)(ws + WS_PROJW);
  if (gid < 196608) qw[gid] = f2b(qkv_w[gid]);
  if (gid < 65536)  pw[gid] = f2b(proj_w[gid]);
  if (gid < 768) {
    float v = 0.f;
    if (gid < 256) v = q_bias[gid];
    else if (gid >= 512) v = v_bias[gid - 512];
    ((float*)(ws + WS_QKVB))[gid] = v;
  }
  if (gid < 8) {
    float ls = logit_scale[gid];
    ((float*)(ws + WS_SCALE))[gid] = __expf(fminf(ls, 4.605170185988091f));
  }
}

__global__ void prep_cpb(const float* __restrict__ w1, const float* __restrict__ b1,
                         const float* __restrict__ w2, unsigned char* __restrict__ ws) {
  __shared__ float hid[512];
  const int r = blockIdx.x;            // 0..224
  const int dh = r / 15, dw = r % 15;
  float t0 = ((float)(dh - 7)) / 7.0f * 8.0f;
  float t1 = ((float)(dw - 7)) / 7.0f * 8.0f;
  float a0 = log2f(fabsf(t0) + 1.0f) / 3.0f;
  float a1 = log2f(fabsf(t1) + 1.0f) / 3.0f;
  t0 = (t0 < 0.f) ? -a0 : a0;
  t1 = (t1 < 0.f) ? -a1 : a1;
  const int j = threadIdx.x;           // 0..511
  float h = t0 * w1[2 * j] + t1 * w1[2 * j + 1] + b1[j];
  hid[j] = fmaxf(h, 0.f);
  __syncthreads();
  const int wave = j >> 6, lane = j & 63;   // wave == head
  float p = 0.f;
  for (int jj = lane; jj < 512; jj += 64) p += hid[jj] * w2[wave * 512 + jj];
  #pragma unroll
  for (int off = 32; off > 0; off >>= 1) p += __shfl_down(p, off, 64);
  if (lane == 0) ((float*)(ws + WS_BT))[r * 8 + wave] = p;
}

// bias pre-swizzled for the TRANSPOSED score layout:
// S^T tile st[jt][it]: i = it*16 + (lane&15), j = jt*16 + (lane>>4)*4 + reg
__global__ void prep_bias(unsigned char* __restrict__ ws) {
  int u = blockIdx.x * 256 + threadIdx.x;   // 0..32767
  int reg = u & 3;
  int lane = (u >> 2) & 63;
  int it = (u >> 8) & 3;
  int jt = (u >> 10) & 3;
  int h = (u >> 12);
  int i = it * 16 + (lane & 15);
  int jx = jt * 16 + (lane >> 4) * 4 + reg;
  int idx = ((i >> 3) - (jx >> 3) + 7) * 15 + ((i & 7) - (jx & 7) + 7);
  float xv = ((const float*)(ws + WS_BT))[idx * 8 + h];
  ((float*)(ws + WS_BIAS))[u] = 16.0f / (1.0f + __expf(-xv));
}

// ---------------- main fused kernel ----------------
// Wave h owns head h end-to-end: QKV GEMM computes q_h,k_h,v_h (96 cols),
// normalize in registers, attention fully per-wave through a private 5 KB
// LDS scratch. 3 barriers total. LDS 74752 B -> 2 blocks/CU.

__launch_bounds__(512, 4)
__global__ void swin_main(const float* __restrict__ x,
                          const unsigned char* __restrict__ ws,
                          float* __restrict__ out,
                          const float* __restrict__ proj_b) {
  extern __shared__ unsigned short sm[];
  const int tid = threadIdx.x;
  const int wave = tid >> 6;
  const int lane = tid & 63;
  const int quad = lane >> 4;
  const int l15 = lane & 15;

  const int blk = blockIdx.x;
  const int b = blk >> 8;
  const int win = blk & 255;
  const int wr = win >> 4;
  const int wc = win & 15;

  const unsigned short* qkvw = (const unsigned short*)(ws + WS_QKVW);
  const unsigned short* projw = (const unsigned short*)(ws + WS_PROJW);
  const float* qkvb = (const float*)(ws + WS_QKVB);
  const float* scales = (const float*)(ws + WS_SCALE);
  const float* bias_sw = (const float*)(ws + WS_BIAS);

  // ---- phase 0: gather shifted window -> xs bf16 [64][264]
  {
    const int t = tid >> 3;          // token 0..63
    const int cg = tid & 7;          // channel group
    const int rw = t >> 3, cw = t & 7;
    const int gr = (wr * 8 + rw + 4) & 127;
    const int gc = (wc * 8 + cw + 4) & 127;
    const float* src = x + ((size_t)b * 16384 + gr * 128 + gc) * 256 + cg * 32;
    unsigned short* dst = sm + XS_US + t * 264 + cg * 32;
    #pragma unroll
    for (int kk = 0; kk < 4; ++kk) {
      f32x4 a = *(const f32x4*)(src + kk * 8);
      f32x4 c = *(const f32x4*)(src + kk * 8 + 4);
      union { bf16x8 v; unsigned short u[8]; } pk;
      #pragma unroll
      for (int e = 0; e < 4; ++e) { pk.u[e] = f2b(a[e]); pk.u[4 + e] = f2b(c[e]); }
      *(bf16x8*)(dst + kk * 8) = pk.v;
    }
  }
  __syncthreads();

  const int h = wave;
  unsigned short* buf = sm + SCR_US + wave * 2560;   // per-wave scratch
  const float sc = scales[h];

  bf16x8 qfr[4], kfr[4];   // attention A/B fragments, kept in registers

  // ---- phase 1a: q,k GEMM (wave computes head h's 64 cols) + in-reg
  //      cosine normalize + fragment extraction via per-wave scratch
  {
    f32x4 accq[4][2], acck[4][2];
    #pragma unroll
    for (int mt = 0; mt < 4; ++mt)
      #pragma unroll
      for (int n2 = 0; n2 < 2; ++n2) {
        accq[mt][n2] = f32x4{0.f, 0.f, 0.f, 0.f};
        acck[mt][n2] = f32x4{0.f, 0.f, 0.f, 0.f};
      }
    for (int k0 = 0; k0 < 256; k0 += 32) {
      bf16x8 afr[4];
      #pragma unroll
      for (int mt = 0; mt < 4; ++mt)
        afr[mt] = *(const bf16x8*)(sm + XS_US + (mt * 16 + l15) * 264 + k0 + quad * 8);
      #pragma unroll
      for (int n2 = 0; n2 < 2; ++n2) {
        const bf16x8 wq = *(const bf16x8*)(qkvw + (size_t)(32 * h + n2 * 16 + l15) * 256 + k0 + quad * 8);
        const bf16x8 wk = *(const bf16x8*)(qkvw + (size_t)(256 + 32 * h + n2 * 16 + l15) * 256 + k0 + quad * 8);
        #pragma unroll
        for (int mt = 0; mt < 4; ++mt) {
          accq[mt][n2] = __builtin_amdgcn_mfma_f32_16x16x32_bf16(afr[mt], wq, accq[mt][n2], 0, 0, 0);
          acck[mt][n2] = __builtin_amdgcn_mfma_f32_16x16x32_bf16(afr[mt], wk, acck[mt][n2], 0, 0, 0);
        }
      }
    }
    // q: +bias, normalize (fold per-head scale). chans of the head live on
    // the 16 l15 lanes x 2 n-tiles -> shuffle-reduce over l15 only.
    const float bq0 = qkvb[32 * h + l15];
    const float bq1 = qkvb[32 * h + 16 + l15];
    #pragma unroll
    for (int mt = 0; mt < 4; ++mt) {
      f32x4 ss;
      #pragma unroll
      for (int r = 0; r < 4; ++r) {
        float a0 = accq[mt][0][r] + bq0;
        float a1 = accq[mt][1][r] + bq1;
        accq[mt][0][r] = a0; accq[mt][1][r] = a1;
        ss[r] = a0 * a0 + a1 * a1;
      }
      #pragma unroll
      for (int off = 1; off < 16; off <<= 1)
        #pragma unroll
        for (int r = 0; r < 4; ++r) ss[r] += __shfl_xor(ss[r], off, 64);
      #pragma unroll
      for (int r = 0; r < 4; ++r) {
        const float inv = sc / fmaxf(sqrtf(ss[r]), 1e-12f);
        accq[mt][0][r] *= inv; accq[mt][1][r] *= inv;
      }
    }
    // k: normalize (bias is zero)
    #pragma unroll
    for (int mt = 0; mt < 4; ++mt) {
      f32x4 ss;
      #pragma unroll
      for (int r = 0; r < 4; ++r) {
        float a0 = acck[mt][0][r], a1 = acck[mt][1][r];
        ss[r] = a0 * a0 + a1 * a1;
      }
      #pragma unroll
      for (int off = 1; off < 16; off <<= 1)
        #pragma unroll
        for (int r = 0; r < 4; ++r) ss[r] += __shfl_xor(ss[r], off, 64);
      #pragma unroll
      for (int r = 0; r < 4; ++r) {
        const float inv = 1.0f / fmaxf(sqrtf(ss[r]), 1e-12f);
        acck[mt][0][r] *= inv; acck[mt][1][r] *= inv;
      }
    }
    // q -> buf [64][40] token-major, read A/B fragments (per-wave: no barrier,
    // DS ops are in-order within a wave)
    #pragma unroll
    for (int mt = 0; mt < 4; ++mt)
      #pragma unroll
      for (int n2 = 0; n2 < 2; ++n2)
        #pragma unroll
        for (int r = 0; r < 4; ++r)
          buf[(mt * 16 + quad * 4 + r) * 40 + n2 * 16 + l15] = f2b(accq[mt][n2][r]);
    #pragma unroll
    for (int mt = 0; mt < 4; ++mt)
      qfr[mt] = *(const bf16x8*)(buf + (mt * 16 + l15) * 40 + quad * 8);
    // k -> same buf, read fragments
    #pragma unroll
    for (int mt = 0; mt < 4; ++mt)
      #pragma unroll
      for (int n2 = 0; n2 < 2; ++n2)
        #pragma unroll
        for (int r = 0; r < 4; ++r)
          buf[(mt * 16 + quad * 4 + r) * 40 + n2 * 16 + l15] = f2b(acck[mt][n2][r]);
    #pragma unroll
    for (int mt = 0; mt < 4; ++mt)
      kfr[mt] = *(const bf16x8*)(buf + (mt * 16 + l15) * 40 + quad * 8);
  }

  // ---- phase 1b: v GEMM, +bias, V^T -> buf [32][72] (packed b64 writes)
  {
    f32x4 accv[4][2];
    #pragma unroll
    for (int mt = 0; mt < 4; ++mt)
      #pragma unroll
      for (int n2 = 0; n2 < 2; ++n2) accv[mt][n2] = f32x4{0.f, 0.f, 0.f, 0.f};
    for (int k0 = 0; k0 < 256; k0 += 32) {
      bf16x8 afr[4];
      #pragma unroll
      for (int mt = 0; mt < 4; ++mt)
        afr[mt] = *(const bf16x8*)(sm + XS_US + (mt * 16 + l15) * 264 + k0 + quad * 8);
      #pragma unroll
      for (int n2 = 0; n2 < 2; ++n2) {
        const bf16x8 wv = *(const bf16x8*)(qkvw + (size_t)(512 + 32 * h + n2 * 16 + l15) * 256 + k0 + quad * 8);
        #pragma unroll
        for (int mt = 0; mt < 4; ++mt)
          accv[mt][n2] = __builtin_amdgcn_mfma_f32_16x16x32_bf16(afr[mt], wv, accv[mt][n2], 0, 0, 0);
      }
    }
    const float bv0 = qkvb[512 + 32 * h + l15];
    const float bv1 = qkvb[512 + 32 * h + 16 + l15];
    #pragma unroll
    for (int mt = 0; mt < 4; ++mt)
      #pragma unroll
      for (int n2 = 0; n2 < 2; ++n2) {
        const float bb = n2 ? bv1 : bv0;
        union { unsigned short u[4]; unsigned long long ll; } pk;
        #pragma unroll
        for (int r = 0; r < 4; ++r) pk.u[r] = f2b(accv[mt][n2][r] + bb);
        *(unsigned long long*)(buf + (n2 * 16 + l15) * 72 + mt * 16 + quad * 4) = pk.ll;
      }
  }

  // ---- phase 2: attention, fully per-wave (no barriers)
  f32x4 o[4][2];
  {
    // swapped QK^T: st[jt][it] = S^T tile, i = it*16+l15, j = jt*16+quad*4+r
    f32x4 st[4][4];
    #pragma unroll
    for (int jt = 0; jt < 4; ++jt)
      #pragma unroll
      for (int it = 0; it < 4; ++it)
        st[jt][it] = __builtin_amdgcn_mfma_f32_16x16x32_bf16(kfr[jt], qfr[it], f32x4{0.f, 0.f, 0.f, 0.f}, 0, 0, 0);

    // + relative-position bias (pre-swizzled for S^T) and shift mask
    const bool has_mask = (wr == 15) || (wc == 15);
    const float* bsw = bias_sw + (size_t)h * 4096 + (size_t)lane * 4;
    #pragma unroll
    for (int jt = 0; jt < 4; ++jt) {
      #pragma unroll
      for (int it = 0; it < 4; ++it) {
        f32x4 bv = *(const f32x4*)(bsw + (jt * 4 + it) * 256);
        #pragma unroll
        for (int r = 0; r < 4; ++r) st[jt][it][r] += bv[r];
        if (has_mask) {
          const int i = it * 16 + l15;
          const int bri = (wr == 15) ? (((i >> 3) < 4) ? 1 : 2) : 0;
          const int bci = (wc == 15) ? (((i & 7) < 4) ? 1 : 2) : 0;
          #pragma unroll
          for (int r = 0; r < 4; ++r) {
            const int j = jt * 16 + quad * 4 + r;
            const int brj = (wr == 15) ? (((j >> 3) < 4) ? 1 : 2) : 0;
            const int bcj = (wc == 15) ? (((j & 7) < 4) ? 1 : 2) : 0;
            if (bri != brj || bci != bcj) st[jt][it][r] -= 100.0f;
          }
        }
      }
    }

    // softmax over j: per-lane over 16 regs + 2 cross-quad shuffles; P is
    // normalized in-register before bf16 conversion.
    #pragma unroll
    for (int it = 0; it < 4; ++it) {
      f32x4 mm;
      #pragma unroll
      for (int r = 0; r < 4; ++r)
        mm[r] = fmaxf(fmaxf(st[0][it][r], st[1][it][r]), fmaxf(st[2][it][r], st[3][it][r]));
      float m = fmaxf(fmaxf(mm[0], mm[1]), fmaxf(mm[2], mm[3]));
      m = fmaxf(m, __shfl_xor(m, 16, 64));
      m = fmaxf(m, __shfl_xor(m, 32, 64));
      f32x4 sv = f32x4{0.f, 0.f, 0.f, 0.f};
      #pragma unroll
      for (int jt = 0; jt < 4; ++jt)
        #pragma unroll
        for (int r = 0; r < 4; ++r) {
          const float p = __expf(st[jt][it][r] - m);
          st[jt][it][r] = p;
          sv[r] += p;
        }
      float sum = (sv[0] + sv[1]) + (sv[2] + sv[3]);
      sum += __shfl_xor(sum, 16, 64);
      sum += __shfl_xor(sum, 32, 64);
      const float rinv = 1.0f / sum;
      #pragma unroll
      for (int jt = 0; jt < 4; ++jt)
        #pragma unroll
        for (int r = 0; r < 4; ++r) st[jt][it][r] *= rinv;
    }

    // V fragments out of buf (before P halves overwrite it)
    bf16x8 vfr[2][2];
    #pragma unroll
    for (int ks = 0; ks < 2; ++ks)
      #pragma unroll
      for (int nc = 0; nc < 2; ++nc)
        vfr[ks][nc] = *(const bf16x8*)(buf + (nc * 16 + l15) * 72 + ks * 32 + quad * 8);

    #pragma unroll
    for (int mt = 0; mt < 4; ++mt)
      #pragma unroll
      for (int nc = 0; nc < 2; ++nc) o[mt][nc] = f32x4{0.f, 0.f, 0.f, 0.f};

    // PV in two j-halves through the same scratch ([64][40] token-major)
    #pragma unroll
    for (int ks = 0; ks < 2; ++ks) {
      #pragma unroll
      for (int it = 0; it < 4; ++it)
        #pragma unroll
        for (int jh = 0; jh < 2; ++jh) {
          const int jt = ks * 2 + jh;
          union { unsigned short u[4]; unsigned long long ll; } pk;
          #pragma unroll
          for (int r = 0; r < 4; ++r) pk.u[r] = f2b(st[jt][it][r]);
          *(unsigned long long*)(buf + (it * 16 + l15) * 40 + jh * 16 + quad * 4) = pk.ll;
        }
      bf16x8 pa[4];
      #pragma unroll
      for (int mt = 0; mt < 4; ++mt)
        pa[mt] = *(const bf16x8*)(buf + (mt * 16 + l15) * 40 + quad * 8);
      #pragma unroll
      for (int nc = 0; nc < 2; ++nc)
        #pragma unroll
        for (int mt = 0; mt < 4; ++mt)
          o[mt][nc] = __builtin_amdgcn_mfma_f32_16x16x32_bf16(pa[mt], vfr[ks][nc], o[mt][nc], 0, 0, 0);
    }
  }

  // all waves are past their last X-tile read once they arrive here
  __syncthreads();

  // O -> attn_out bf16 [64][264] (reuses xs region)
  #pragma unroll
  for (int mt = 0; mt < 4; ++mt)
    #pragma unroll
    for (int nc = 0; nc < 2; ++nc)
      #pragma unroll
      for (int r = 0; r < 4; ++r)
        sm[XS_US + (mt * 16 + quad * 4 + r) * 264 + h * 32 + nc * 16 + l15] = f2b(o[mt][nc][r]);
  __syncthreads();

  // ---- phase 3: proj GEMM (64x256 = attn_out @ Wp^T) + unshift scatter-store
  {
    f32x4 acc[4][2];
    #pragma unroll
    for (int mt = 0; mt < 4; ++mt)
      #pragma unroll
      for (int nt = 0; nt < 2; ++nt) acc[mt][nt] = f32x4{0.f, 0.f, 0.f, 0.f};
    const int ncol0 = wave * 32;
    for (int k0 = 0; k0 < 256; k0 += 32) {
      bf16x8 afr[4];
      #pragma unroll
      for (int mt = 0; mt < 4; ++mt)
        afr[mt] = *(const bf16x8*)(sm + XS_US + (mt * 16 + l15) * 264 + k0 + quad * 8);
      #pragma unroll
      for (int nt = 0; nt < 2; ++nt) {
        const int n = ncol0 + nt * 16 + l15;
        bf16x8 bfr = *(const bf16x8*)(projw + (size_t)n * 256 + k0 + quad * 8);
        #pragma unroll
        for (int mt = 0; mt < 4; ++mt)
          acc[mt][nt] = __builtin_amdgcn_mfma_f32_16x16x32_bf16(afr[mt], bfr, acc[mt][nt], 0, 0, 0);
      }
    }
    #pragma unroll
    for (int nt = 0; nt < 2; ++nt) {
      const int col = ncol0 + nt * 16 + l15;
      const float pb = proj_b[col];
      #pragma unroll
      for (int mt = 0; mt < 4; ++mt) {
        #pragma unroll
        for (int r = 0; r < 4; ++r) {
          const int tok = mt * 16 + quad * 4 + r;
          const int rw = tok >> 3, cw = tok & 7;
          const int gr = (wr * 8 + rw + 4) & 127;
          const int gc = (wc * 8 + cw + 4) & 127;
          out[((size_t)b * 16384 + gr * 128 + gc) * 256 + col] = acc[mt][nt][r] + pb;
        }
      }
    }
  }
}

// ---------------- launch ----------------

extern "C" void kernel_launch(void* const* d_in, const int* in_sizes, int n_in,
                              void* d_out, int out_size, void* d_ws, size_t ws_size,
                              hipStream_t stream) {
  const float* x           = (const float*)d_in[0];
  const float* qkv_w       = (const float*)d_in[1];
  const float* q_bias      = (const float*)d_in[2];
  const float* v_bias      = (const float*)d_in[3];
  const float* logit_scale = (const float*)d_in[4];
  const float* cpb_w1      = (const float*)d_in[5];
  const float* cpb_b1      = (const float*)d_in[6];
  const float* cpb_w2      = (const float*)d_in[7];
  const float* proj_w      = (const float*)d_in[8];
  const float* proj_b      = (const float*)d_in[9];
  unsigned char* ws = (unsigned char*)d_ws;
  float* out = (float*)d_out;

  prep_weights<<<768, 256, 0, stream>>>(qkv_w, q_bias, v_bias, logit_scale, proj_w, ws);
  prep_cpb<<<225, 512, 0, stream>>>(cpb_w1, cpb_b1, cpb_w2, ws);
  prep_bias<<<128, 256, 0, stream>>>(ws);

  (void)hipFuncSetAttribute((const void*)swin_main,
                            hipFuncAttributeMaxDynamicSharedMemorySize, SMEM_BYTES);
  swin_main<<<2048, 512, SMEM_BYTES, stream>>>(x, ws, out, proj_b);
}

// Round 3
// 404.287 us; speedup vs baseline: 1.2155x; 1.0027x over previous
//
#include <hip/hip_runtime.h>
#include <cstdint>
#include <cstddef>

typedef short bf16x8 __attribute__((ext_vector_type(8)));
typedef float f32x4 __attribute__((ext_vector_type(4)));

// ---- problem constants ----
// B=8, H=W=128, C=256, heads=8, hd=32, ws=8, shift=4, N=64 tokens/window,
// 16x16 windows/image, 2048 windows total.

// ---- workspace layout (byte offsets) ----
#define WS_QKVW   0u          // bf16 [768][256]
#define WS_PROJW  393216u     // bf16 [256][256]
#define WS_QKVB   524288u     // f32  [768]  (q_bias, 0, v_bias)
#define WS_SCALE  527360u     // f32  [8]    exp(min(logit_scale, ln 100))
#define WS_BT     527392u     // f32  [225][8] cpb table
#define WS_BIAS   534592u     // f32  [8][4(jt)][4(it)][64][4]  (S^T-layout swizzled)
// total needed: 665664 bytes

// ---- LDS layout (ushort units) ----
// X window [64][264] (reused as attn_out), then 8 per-wave scratch bufs of
// 2944 us each: q/k staging [64][40] (timeshared) -> V^T [32][72] @0 with
// P half-strip [16][40] @2304.
#define XS_US      0
#define SCR_US     16896
#define SCR_STRIDE 2944
#define STRIP_OFF  2304
#define SMEM_US    (16896 + 8 * SCR_STRIDE)   // 40448 us
#define SMEM_BYTES (SMEM_US * 2)              // 80896 B -> 2 blocks/CU

// compiler-only ordering fence: forbids reordering of the type-punned LDS
// stores/loads across it (DS pipe is in-order per wave, so HW needs nothing)
#define MEMFENCE() asm volatile("" ::: "memory")

__device__ __forceinline__ unsigned short f2b(float f) {
  union { float f; unsigned int u; } v; v.f = f;
  return (unsigned short)((v.u + 0x7FFFu + ((v.u >> 16) & 1u)) >> 16);
}

// ---------------- prep kernels ----------------

__global__ void prep_weights(const float* __restrict__ qkv_w,
                             const float* __restrict__ q_bias,
                             const float* __restrict__ v_bias,
                             const float* __restrict__ logit_scale,
                             const float* __restrict__ proj_w,
                             unsigned char* __restrict__ ws) {
  int gid = blockIdx.x * 256 + threadIdx.x;            // 0 .. 196607
  unsigned short* qw = (unsigned short*)(ws + WS_QKVW);
  unsigned short* pw = (unsigned short*)(ws + WS_PROJW);
  if (gid < 196608) qw[gid] = f2b(qkv_w[gid]);
  if (gid < 65536)  pw[gid] = f2b(proj_w[gid]);
  if (gid < 768) {
    float v = 0.f;
    if (gid < 256) v = q_bias[gid];
    else if (gid >= 512) v = v_bias[gid - 512];
    ((float*)(ws + WS_QKVB))[gid] = v;
  }
  if (gid < 8) {
    float ls = logit_scale[gid];
    ((float*)(ws + WS_SCALE))[gid] = __expf(fminf(ls, 4.605170185988091f));
  }
}

__global__ void prep_cpb(const float* __restrict__ w1, const float* __restrict__ b1,
                         const float* __restrict__ w2, unsigned char* __restrict__ ws) {
  __shared__ float hid[512];
  const int r = blockIdx.x;            // 0..224
  const int dh = r / 15, dw = r % 15;
  float t0 = ((float)(dh - 7)) / 7.0f * 8.0f;
  float t1 = ((float)(dw - 7)) / 7.0f * 8.0f;
  float a0 = log2f(fabsf(t0) + 1.0f) / 3.0f;
  float a1 = log2f(fabsf(t1) + 1.0f) / 3.0f;
  t0 = (t0 < 0.f) ? -a0 : a0;
  t1 = (t1 < 0.f) ? -a1 : a1;
  const int j = threadIdx.x;           // 0..511
  float h = t0 * w1[2 * j] + t1 * w1[2 * j + 1] + b1[j];
  hid[j] = fmaxf(h, 0.f);
  __syncthreads();
  const int wave = j >> 6, lane = j & 63;   // wave == head
  float p = 0.f;
  for (int jj = lane; jj < 512; jj += 64) p += hid[jj] * w2[wave * 512 + jj];
  #pragma unroll
  for (int off = 32; off > 0; off >>= 1) p += __shfl_down(p, off, 64);
  if (lane == 0) ((float*)(ws + WS_BT))[r * 8 + wave] = p;
}

// bias pre-swizzled for the TRANSPOSED score layout:
// S^T tile st[jt][it]: i = it*16 + (lane&15), j = jt*16 + (lane>>4)*4 + reg
__global__ void prep_bias(unsigned char* __restrict__ ws) {
  int u = blockIdx.x * 256 + threadIdx.x;   // 0..32767
  int reg = u & 3;
  int lane = (u >> 2) & 63;
  int it = (u >> 8) & 3;
  int jt = (u >> 10) & 3;
  int h = (u >> 12);
  int i = it * 16 + (lane & 15);
  int jx = jt * 16 + (lane >> 4) * 4 + reg;
  int idx = ((i >> 3) - (jx >> 3) + 7) * 15 + ((i & 7) - (jx & 7) + 7);
  float xv = ((const float*)(ws + WS_BT))[idx * 8 + h];
  ((float*)(ws + WS_BIAS))[u] = 16.0f / (1.0f + __expf(-xv));
}

// ---------------- main fused kernel ----------------
// Wave h owns head h end-to-end. Attention is STREAMED one it-tile at a
// time (S^T column group of 16 rows): peak live regs ~110 < 128 so the
// 4-waves/EU bound holds without spilling.

__launch_bounds__(512, 4)
__global__ void swin_main(const float* __restrict__ x,
                          const unsigned char* __restrict__ ws,
                          float* __restrict__ out,
                          const float* __restrict__ proj_b) {
  extern __shared__ unsigned short sm[];
  const int tid = threadIdx.x;
  const int wave = tid >> 6;
  const int lane = tid & 63;
  const int quad = lane >> 4;
  const int l15 = lane & 15;

  const int blk = blockIdx.x;
  const int b = blk >> 8;
  const int win = blk & 255;
  const int wr = win >> 4;
  const int wc = win & 15;

  const unsigned short* qkvw = (const unsigned short*)(ws + WS_QKVW);
  const unsigned short* projw = (const unsigned short*)(ws + WS_PROJW);
  const float* qkvb = (const float*)(ws + WS_QKVB);
  const float* scales = (const float*)(ws + WS_SCALE);
  const float* bias_sw = (const float*)(ws + WS_BIAS);

  // ---- phase 0: gather shifted window -> xs bf16 [64][264]
  {
    const int t = tid >> 3;          // token 0..63
    const int cg = tid & 7;          // channel group
    const int rw = t >> 3, cw = t & 7;
    const int gr = (wr * 8 + rw + 4) & 127;
    const int gc = (wc * 8 + cw + 4) & 127;
    const float* src = x + ((size_t)b * 16384 + gr * 128 + gc) * 256 + cg * 32;
    unsigned short* dst = sm + XS_US + t * 264 + cg * 32;
    #pragma unroll
    for (int kk = 0; kk < 4; ++kk) {
      f32x4 a = *(const f32x4*)(src + kk * 8);
      f32x4 c = *(const f32x4*)(src + kk * 8 + 4);
      union { bf16x8 v; unsigned short u[8]; } pk;
      #pragma unroll
      for (int e = 0; e < 4; ++e) { pk.u[e] = f2b(a[e]); pk.u[4 + e] = f2b(c[e]); }
      *(bf16x8*)(dst + kk * 8) = pk.v;
    }
  }
  __syncthreads();

  const int h = wave;
  unsigned short* buf = sm + SCR_US + wave * SCR_STRIDE;   // per-wave scratch
  const float sc = scales[h];

  bf16x8 qfr[4], kfr[4];   // attention A/B fragments, kept in registers

  // ---- phase 1a: q,k GEMM (wave computes head h's 64 cols) + in-reg
  //      cosine normalize + fragment extraction via per-wave scratch
  {
    f32x4 accq[4][2], acck[4][2];
    #pragma unroll
    for (int mt = 0; mt < 4; ++mt)
      #pragma unroll
      for (int n2 = 0; n2 < 2; ++n2) {
        accq[mt][n2] = f32x4{0.f, 0.f, 0.f, 0.f};
        acck[mt][n2] = f32x4{0.f, 0.f, 0.f, 0.f};
      }
    for (int k0 = 0; k0 < 256; k0 += 32) {
      bf16x8 afr[4];
      #pragma unroll
      for (int mt = 0; mt < 4; ++mt)
        afr[mt] = *(const bf16x8*)(sm + XS_US + (mt * 16 + l15) * 264 + k0 + quad * 8);
      #pragma unroll
      for (int n2 = 0; n2 < 2; ++n2) {
        const bf16x8 wq = *(const bf16x8*)(qkvw + (size_t)(32 * h + n2 * 16 + l15) * 256 + k0 + quad * 8);
        const bf16x8 wk = *(const bf16x8*)(qkvw + (size_t)(256 + 32 * h + n2 * 16 + l15) * 256 + k0 + quad * 8);
        #pragma unroll
        for (int mt = 0; mt < 4; ++mt) {
          accq[mt][n2] = __builtin_amdgcn_mfma_f32_16x16x32_bf16(afr[mt], wq, accq[mt][n2], 0, 0, 0);
          acck[mt][n2] = __builtin_amdgcn_mfma_f32_16x16x32_bf16(afr[mt], wk, acck[mt][n2], 0, 0, 0);
        }
      }
    }
    // q: +bias, normalize (fold per-head scale); chans on 16 l15-lanes x 2 n2
    const float bq0 = qkvb[32 * h + l15];
    const float bq1 = qkvb[32 * h + 16 + l15];
    #pragma unroll
    for (int mt = 0; mt < 4; ++mt) {
      f32x4 ss;
      #pragma unroll
      for (int r = 0; r < 4; ++r) {
        float a0 = accq[mt][0][r] + bq0;
        float a1 = accq[mt][1][r] + bq1;
        accq[mt][0][r] = a0; accq[mt][1][r] = a1;
        ss[r] = a0 * a0 + a1 * a1;
      }
      #pragma unroll
      for (int off = 1; off < 16; off <<= 1)
        #pragma unroll
        for (int r = 0; r < 4; ++r) ss[r] += __shfl_xor(ss[r], off, 64);
      #pragma unroll
      for (int r = 0; r < 4; ++r) {
        const float inv = sc / fmaxf(sqrtf(ss[r]), 1e-12f);
        accq[mt][0][r] *= inv; accq[mt][1][r] *= inv;
      }
    }
    // k: normalize (bias is zero)
    #pragma unroll
    for (int mt = 0; mt < 4; ++mt) {
      f32x4 ss;
      #pragma unroll
      for (int r = 0; r < 4; ++r)
        ss[r] = acck[mt][0][r] * acck[mt][0][r] + acck[mt][1][r] * acck[mt][1][r];
      #pragma unroll
      for (int off = 1; off < 16; off <<= 1)
        #pragma unroll
        for (int r = 0; r < 4; ++r) ss[r] += __shfl_xor(ss[r], off, 64);
      #pragma unroll
      for (int r = 0; r < 4; ++r) {
        const float inv = 1.0f / fmaxf(sqrtf(ss[r]), 1e-12f);
        acck[mt][0][r] *= inv; acck[mt][1][r] *= inv;
      }
    }
    // q -> buf [64][40] token-major, read A/B fragments
    #pragma unroll
    for (int mt = 0; mt < 4; ++mt)
      #pragma unroll
      for (int n2 = 0; n2 < 2; ++n2)
        #pragma unroll
        for (int r = 0; r < 4; ++r)
          buf[(mt * 16 + quad * 4 + r) * 40 + n2 * 16 + l15] = f2b(accq[mt][n2][r]);
    MEMFENCE();
    #pragma unroll
    for (int mt = 0; mt < 4; ++mt)
      qfr[mt] = *(const bf16x8*)(buf + (mt * 16 + l15) * 40 + quad * 8);
    MEMFENCE();
    // k -> same buf, read fragments
    #pragma unroll
    for (int mt = 0; mt < 4; ++mt)
      #pragma unroll
      for (int n2 = 0; n2 < 2; ++n2)
        #pragma unroll
        for (int r = 0; r < 4; ++r)
          buf[(mt * 16 + quad * 4 + r) * 40 + n2 * 16 + l15] = f2b(acck[mt][n2][r]);
    MEMFENCE();
    #pragma unroll
    for (int mt = 0; mt < 4; ++mt)
      kfr[mt] = *(const bf16x8*)(buf + (mt * 16 + l15) * 40 + quad * 8);
    MEMFENCE();
  }

  // ---- phase 1b: v GEMM, +bias, V^T -> buf [32][72] (packed b64 writes)
  {
    f32x4 accv[4][2];
    #pragma unroll
    for (int mt = 0; mt < 4; ++mt)
      #pragma unroll
      for (int n2 = 0; n2 < 2; ++n2) accv[mt][n2] = f32x4{0.f, 0.f, 0.f, 0.f};
    for (int k0 = 0; k0 < 256; k0 += 32) {
      bf16x8 afr[4];
      #pragma unroll
      for (int mt = 0; mt < 4; ++mt)
        afr[mt] = *(const bf16x8*)(sm + XS_US + (mt * 16 + l15) * 264 + k0 + quad * 8);
      #pragma unroll
      for (int n2 = 0; n2 < 2; ++n2) {
        const bf16x8 wv = *(const bf16x8*)(qkvw + (size_t)(512 + 32 * h + n2 * 16 + l15) * 256 + k0 + quad * 8);
        #pragma unroll
        for (int mt = 0; mt < 4; ++mt)
          accv[mt][n2] = __builtin_amdgcn_mfma_f32_16x16x32_bf16(afr[mt], wv, accv[mt][n2], 0, 0, 0);
      }
    }
    const float bv0 = qkvb[512 + 32 * h + l15];
    const float bv1 = qkvb[512 + 32 * h + 16 + l15];
    #pragma unroll
    for (int mt = 0; mt < 4; ++mt)
      #pragma unroll
      for (int n2 = 0; n2 < 2; ++n2) {
        const float bb = n2 ? bv1 : bv0;
        union { unsigned short u[4]; unsigned long long ll; } pk;
        #pragma unroll
        for (int r = 0; r < 4; ++r) pk.u[r] = f2b(accv[mt][n2][r] + bb);
        *(unsigned long long*)(buf + (n2 * 16 + l15) * 72 + mt * 16 + quad * 4) = pk.ll;
      }
    MEMFENCE();
  }

  // ---- phase 2: attention, fully per-wave, STREAMED per it-tile
  f32x4 o[4][2];
  {
    // V fragments out of buf
    bf16x8 vfr[2][2];
    #pragma unroll
    for (int ks = 0; ks < 2; ++ks)
      #pragma unroll
      for (int nc = 0; nc < 2; ++nc)
        vfr[ks][nc] = *(const bf16x8*)(buf + (nc * 16 + l15) * 72 + ks * 32 + quad * 8);
    MEMFENCE();

    unsigned short* strip = buf + STRIP_OFF;   // P half-strip [16][40]
    const bool has_mask = (wr == 15) || (wc == 15);
    const float* bsw = bias_sw + (size_t)h * 4096 + (size_t)lane * 4;

    #pragma unroll
    for (int it = 0; it < 4; ++it) {
      // QK^T column tile: s_c[jt] = S^T(i = it*16+l15, j = jt*16+quad*4+r)
      f32x4 s_c[4];
      #pragma unroll
      for (int jt = 0; jt < 4; ++jt)
        s_c[jt] = __builtin_amdgcn_mfma_f32_16x16x32_bf16(kfr[jt], qfr[it], f32x4{0.f, 0.f, 0.f, 0.f}, 0, 0, 0);

      // + bias (pre-swizzled) and shift mask
      const int i = it * 16 + l15;
      const int bri = (wr == 15) ? (((i >> 3) < 4) ? 1 : 2) : 0;
      const int bci = (wc == 15) ? (((i & 7) < 4) ? 1 : 2) : 0;
      #pragma unroll
      for (int jt = 0; jt < 4; ++jt) {
        f32x4 bv = *(const f32x4*)(bsw + (jt * 4 + it) * 256);
        #pragma unroll
        for (int r = 0; r < 4; ++r) s_c[jt][r] += bv[r];
        if (has_mask) {
          #pragma unroll
          for (int r = 0; r < 4; ++r) {
            const int j = jt * 16 + quad * 4 + r;
            const int brj = (wr == 15) ? (((j >> 3) < 4) ? 1 : 2) : 0;
            const int bcj = (wc == 15) ? (((j & 7) < 4) ? 1 : 2) : 0;
            if (bri != brj || bci != bcj) s_c[jt][r] -= 100.0f;
          }
        }
      }

      // softmax over j (full row present: 16 regs + 2 cross-quad shuffles)
      f32x4 mm;
      #pragma unroll
      for (int r = 0; r < 4; ++r)
        mm[r] = fmaxf(fmaxf(s_c[0][r], s_c[1][r]), fmaxf(s_c[2][r], s_c[3][r]));
      float m = fmaxf(fmaxf(mm[0], mm[1]), fmaxf(mm[2], mm[3]));
      m = fmaxf(m, __shfl_xor(m, 16, 64));
      m = fmaxf(m, __shfl_xor(m, 32, 64));
      f32x4 sv = f32x4{0.f, 0.f, 0.f, 0.f};
      #pragma unroll
      for (int jt = 0; jt < 4; ++jt)
        #pragma unroll
        for (int r = 0; r < 4; ++r) {
          const float p = __expf(s_c[jt][r] - m);
          s_c[jt][r] = p;
          sv[r] += p;
        }
      float sum = (sv[0] + sv[1]) + (sv[2] + sv[3]);
      sum += __shfl_xor(sum, 16, 64);
      sum += __shfl_xor(sum, 32, 64);
      const float rinv = 1.0f / sum;
      #pragma unroll
      for (int jt = 0; jt < 4; ++jt)
        #pragma unroll
        for (int r = 0; r < 4; ++r) s_c[jt][r] *= rinv;

      // PV for this it-tile, j in two halves through the half-strip
      o[it][0] = f32x4{0.f, 0.f, 0.f, 0.f};
      o[it][1] = f32x4{0.f, 0.f, 0.f, 0.f};
      #pragma unroll
      for (int ks = 0; ks < 2; ++ks) {
        MEMFENCE();
        #pragma unroll
        for (int jh = 0; jh < 2; ++jh) {
          const int jt = ks * 2 + jh;
          union { unsigned short u[4]; unsigned long long ll; } pk;
          #pragma unroll
          for (int r = 0; r < 4; ++r) pk.u[r] = f2b(s_c[jt][r]);
          *(unsigned long long*)(strip + l15 * 40 + jh * 16 + quad * 4) = pk.ll;
        }
        MEMFENCE();
        const bf16x8 pa = *(const bf16x8*)(strip + l15 * 40 + quad * 8);
        #pragma unroll
        for (int nc = 0; nc < 2; ++nc)
          o[it][nc] = __builtin_amdgcn_mfma_f32_16x16x32_bf16(pa, vfr[ks][nc], o[it][nc], 0, 0, 0);
        MEMFENCE();
      }
    }
  }

  // all waves are past their last X-tile read once they arrive here
  __syncthreads();

  // O -> attn_out bf16 [64][264] (reuses xs region); rows i = it*16+quad*4+r
  #pragma unroll
  for (int it = 0; it < 4; ++it)
    #pragma unroll
    for (int nc = 0; nc < 2; ++nc)
      #pragma unroll
      for (int r = 0; r < 4; ++r)
        sm[XS_US + (it * 16 + quad * 4 + r) * 264 + h * 32 + nc * 16 + l15] = f2b(o[it][nc][r]);
  __syncthreads();

  // ---- phase 3: proj GEMM (64x256 = attn_out @ Wp^T) + unshift scatter-store
  {
    f32x4 acc[4][2];
    #pragma unroll
    for (int mt = 0; mt < 4; ++mt)
      #pragma unroll
      for (int nt = 0; nt < 2; ++nt) acc[mt][nt] = f32x4{0.f, 0.f, 0.f, 0.f};
    const int ncol0 = wave * 32;
    for (int k0 = 0; k0 < 256; k0 += 32) {
      bf16x8 afr[4];
      #pragma unroll
      for (int mt = 0; mt < 4; ++mt)
        afr[mt] = *(const bf16x8*)(sm + XS_US + (mt * 16 + l15) * 264 + k0 + quad * 8);
      #pragma unroll
      for (int nt = 0; nt < 2; ++nt) {
        const int n = ncol0 + nt * 16 + l15;
        bf16x8 bfr = *(const bf16x8*)(projw + (size_t)n * 256 + k0 + quad * 8);
        #pragma unroll
        for (int mt = 0; mt < 4; ++mt)
          acc[mt][nt] = __builtin_amdgcn_mfma_f32_16x16x32_bf16(afr[mt], bfr, acc[mt][nt], 0, 0, 0);
      }
    }
    #pragma unroll
    for (int nt = 0; nt < 2; ++nt) {
      const int col = ncol0 + nt * 16 + l15;
      const float pb = proj_b[col];
      #pragma unroll
      for (int mt = 0; mt < 4; ++mt) {
        #pragma unroll
        for (int r = 0; r < 4; ++r) {
          const int tok = mt * 16 + quad * 4 + r;
          const int rw = tok >> 3, cw = tok & 7;
          const int gr = (wr * 8 + rw + 4) & 127;
          const int gc = (wc * 8 + cw + 4) & 127;
          out[((size_t)b * 16384 + gr * 128 + gc) * 256 + col] = acc[mt][nt][r] + pb;
        }
      }
    }
  }
}

// ---------------- launch ----------------

extern "C" void kernel_launch(void* const* d_in, const int* in_sizes, int n_in,
                              void* d_out, int out_size, void* d_ws, size_t ws_size,
                              hipStream_t stream) {
  const float* x           = (const float*)d_in[0];
  const float* qkv_w       = (const float*)d_in[1];
  const float* q_bias      = (const float*)d_in[2];
  const float* v_bias      = (const float*)d_in[3];
  const float* logit_scale = (const float*)d_in[4];
  const float* cpb_w1      = (const float*)d_in[5];
  const float* cpb_b1      = (const float*)d_in[6];
  const float* cpb_w2      = (const float*)d_in[7];
  const float* proj_w      = (const float*)d_in[8];
  const float* proj_b      = (const float*)d_in[9];
  unsigned char* ws = (unsigned char*)d_ws;
  float* out = (float*)d_out;

  prep_weights<<<768, 256, 0, stream>>>(qkv_w, q_bias, v_bias, logit_scale, proj_w, ws);
  prep_cpb<<<225, 512, 0, stream>>>(cpb_w1, cpb_b1, cpb_w2, ws);
  prep_bias<<<128, 256, 0, stream>>>(ws);

  (void)hipFuncSetAttribute((const void*)swin_main,
                            hipFuncAttributeMaxDynamicSharedMemorySize, SMEM_BYTES);
  swin_main<<<2048, 512, SMEM_BYTES, stream>>>(x, ws, out, proj_b);
}